// Round 3
// baseline (45.270 us; speedup 1.0000x reference)
//
#include <hip/hip_runtime.h>
#include <math.h>

// Second-order cone projection over 3 fixed groups:
//   (d=4,  m=2,000,000)  floats [0, 8M)
//   (d=8,  m=1,000,000)  floats [8M, 16M)
//   (d=16, m=  500,000)  floats [16M, 24M)
// Per row [t, z...]: nz = max(||z||, 1e-12)
//   nz <= t+eps  -> identity
//   nz <= -t     -> zero
//   else         -> 0.5*(1 + t/nz) * [nz, z...]
// Memory-bound: 96 MB read + 96 MB write.
// R1: 35.3 us (5.44 TB/s effective). R3: nontemporal stores via native
// ext_vector_type (float4 is a HIP class the builtin rejects).

#define SOC_EPS 1e-12f

typedef float floatx4 __attribute__((ext_vector_type(4)));

template<int D>
__device__ __forceinline__ void proj_row(const float* __restrict__ in,
                                         float* __restrict__ out,
                                         long long row, long long m) {
    if (row >= m) return;
    const floatx4* ip = reinterpret_cast<const floatx4*>(in) + row * (D / 4);
    floatx4* op = reinterpret_cast<floatx4*>(out) + row * (D / 4);

    float r[D];
#pragma unroll
    for (int i = 0; i < D / 4; ++i) {
        floatx4 v = ip[i];
        r[4 * i + 0] = v.x;
        r[4 * i + 1] = v.y;
        r[4 * i + 2] = v.z;
        r[4 * i + 3] = v.w;
    }

    float t = r[0];
    float ss = 0.0f;
#pragma unroll
    for (int j = 1; j < D; ++j) ss = fmaf(r[j], r[j], ss);
    float nz = fmaxf(sqrtf(ss), SOC_EPS);

    bool in_cone  = (nz <= t + SOC_EPS);
    bool in_polar = (nz <= -t);
    float c = 0.5f * (1.0f + t / nz);   // nz >= 1e-12 > 0, never div-by-0

    float o[D];
    o[0] = in_cone ? t : (in_polar ? 0.0f : c * nz);
#pragma unroll
    for (int j = 1; j < D; ++j)
        o[j] = in_cone ? r[j] : (in_polar ? 0.0f : c * r[j]);

#pragma unroll
    for (int i = 0; i < D / 4; ++i) {
        floatx4 v;
        v.x = o[4 * i + 0];
        v.y = o[4 * i + 1];
        v.z = o[4 * i + 2];
        v.w = o[4 * i + 3];
        __builtin_nontemporal_store(v, &op[i]);   // streaming store: don't pollute L2/L3
    }
}

__global__ __launch_bounds__(256)
void SecondOrderConeProjector_kernel(const float* __restrict__ x,
                                     float* __restrict__ out,
                                     int nb0, int nb1,
                                     long long m0, long long m1, long long m2,
                                     long long off1, long long off2) {
    int b = blockIdx.x;
    if (b < nb0) {
        long long row = (long long)b * blockDim.x + threadIdx.x;
        proj_row<4>(x, out, row, m0);
    } else if (b < nb0 + nb1) {
        long long row = (long long)(b - nb0) * blockDim.x + threadIdx.x;
        proj_row<8>(x + off1, out + off1, row, m1);
    } else {
        long long row = (long long)(b - nb0 - nb1) * blockDim.x + threadIdx.x;
        proj_row<16>(x + off2, out + off2, row, m2);
    }
}

extern "C" void kernel_launch(void* const* d_in, const int* in_sizes, int n_in,
                              void* d_out, int out_size, void* d_ws, size_t ws_size,
                              hipStream_t stream) {
    const float* x = (const float*)d_in[0];
    float* out = (float*)d_out;

    const long long m0 = 2000000, m1 = 1000000, m2 = 500000;
    const long long off1 = 4 * m0;            // 8,000,000 floats
    const long long off2 = off1 + 8 * m1;     // 16,000,000 floats

    const int block = 256;
    const int nb0 = (int)((m0 + block - 1) / block);  // 7813
    const int nb1 = (int)((m1 + block - 1) / block);  // 3907
    const int nb2 = (int)((m2 + block - 1) / block);  // 1954
    const int grid = nb0 + nb1 + nb2;

    SecondOrderConeProjector_kernel<<<grid, block, 0, stream>>>(
        x, out, nb0, nb1, m0, m1, m2, off1, off2);
}

// Round 4
// 32.685 us; speedup vs baseline: 1.3850x; 1.3850x over previous
//
#include <hip/hip_runtime.h>
#include <math.h>

// Second-order cone projection over 3 fixed groups:
//   (d=4,  m=2,000,000)  floats [0, 8M)
//   (d=8,  m=1,000,000)  floats [8M, 16M)
//   (d=16, m=  500,000)  floats [16M, 24M)
// Per row [t, z...]: nz = max(||z||, 1e-12)
//   nz <= t+eps  -> identity ; nz <= -t -> zero ; else 0.5*(1+t/nz)*[nz, z...]
//
// R1: thread-per-row, 35.3 us (5.44 TB/s eff). R3: NT stores REGRESSED
// (45.3 us, WRITE_SIZE rose to ~120 MB) -> reverted.
// R4: thread-per-float4-quad for perfect lane-contiguous coalescing on all
// groups; rows shared by 2 (d=8) / 4 (d=16) adjacent lanes, norm via
// __shfl_xor butterfly, t broadcast via __shfl.

#define SOC_EPS 1e-12f

typedef float floatx4 __attribute__((ext_vector_type(4)));

template<int QPR>  // quads per row: 1 (d=4), 2 (d=8), 4 (d=16)
__device__ __forceinline__ void proj_quads(const float* __restrict__ in,
                                           float* __restrict__ out,
                                           long long q, long long nq) {
    if (q >= nq) return;
    const floatx4* ip = reinterpret_cast<const floatx4*>(in);
    floatx4* op = reinterpret_cast<floatx4*>(out);

    floatx4 v = ip[q];                 // lane-contiguous: lane i -> quad i
    int sub = (int)(q & (QPR - 1));    // position of this quad within its row

    // partial sum of squares over this quad's z-elements
    float ssq = fmaf(v.y, v.y, fmaf(v.z, v.z, v.w * v.w));
    if (QPR > 1 && sub != 0) ssq = fmaf(v.x, v.x, ssq);  // elem0 is z unless first quad

    // reduce across the row's lane group (aligned: block offsets are %256)
    float tot = ssq;
    if (QPR >= 2) tot += __shfl_xor(tot, 1);
    if (QPR >= 4) tot += __shfl_xor(tot, 2);

    // t lives in elem0 of the row's first quad (group's lane 0)
    float t;
    if (QPR == 1) t = v.x;
    else          t = __shfl(v.x, ((int)(threadIdx.x & 63)) & ~(QPR - 1));

    float nz = fmaxf(sqrtf(tot), SOC_EPS);
    bool cone  = (nz <= t + SOC_EPS);
    bool polar = (nz <= -t);
    float c = 0.5f * (1.0f + t / nz);  // nz >= 1e-12 > 0

    // projected elem0 of first quad is c*nz; everything else is c*elem
    float px = (QPR == 1 || sub == 0) ? nz : v.x;

    floatx4 o;
    o.x = cone ? v.x : (polar ? 0.0f : c * px);
    o.y = cone ? v.y : (polar ? 0.0f : c * v.y);
    o.z = cone ? v.z : (polar ? 0.0f : c * v.z);
    o.w = cone ? v.w : (polar ? 0.0f : c * v.w);
    op[q] = o;                          // lane-contiguous store
}

__global__ __launch_bounds__(256)
void SecondOrderConeProjector_kernel(const float* __restrict__ x,
                                     float* __restrict__ out,
                                     int nb0, int nb1,
                                     long long nq0, long long nq1, long long nq2,
                                     long long off1, long long off2) {
    int b = blockIdx.x;
    if (b < nb0) {
        long long q = (long long)b * blockDim.x + threadIdx.x;
        proj_quads<1>(x, out, q, nq0);
    } else if (b < nb0 + nb1) {
        long long q = (long long)(b - nb0) * blockDim.x + threadIdx.x;
        proj_quads<2>(x + off1, out + off1, q, nq1);
    } else {
        long long q = (long long)(b - nb0 - nb1) * blockDim.x + threadIdx.x;
        proj_quads<4>(x + off2, out + off2, q, nq2);
    }
}

extern "C" void kernel_launch(void* const* d_in, const int* in_sizes, int n_in,
                              void* d_out, int out_size, void* d_ws, size_t ws_size,
                              hipStream_t stream) {
    const float* x = (const float*)d_in[0];
    float* out = (float*)d_out;

    const long long m0 = 2000000, m1 = 1000000, m2 = 500000;
    const long long off1 = 4 * m0;            // 8,000,000 floats
    const long long off2 = off1 + 8 * m1;     // 16,000,000 floats

    const long long nq0 = m0;                 // 2,000,000 quads (d=4)
    const long long nq1 = 2 * m1;             // 2,000,000 quads (d=8)
    const long long nq2 = 4 * m2;             // 2,000,000 quads (d=16)

    const int block = 256;
    const int nb0 = (int)((nq0 + block - 1) / block);  // 7813
    const int nb1 = (int)((nq1 + block - 1) / block);  // 7813
    const int nb2 = (int)((nq2 + block - 1) / block);  // 7813
    const int grid = nb0 + nb1 + nb2;

    SecondOrderConeProjector_kernel<<<grid, block, 0, stream>>>(
        x, out, nb0, nb1, nq0, nq1, nq2, off1, off2);
}